// Round 9
// baseline (419.968 us; speedup 1.0000x reference)
//
#include <hip/hip_runtime.h>
#include <hip/hip_bf16.h>

#define Bz 4
#define Sz 2048
#define Dz 1024
#define Hz 16
#define DHz 64

typedef __bf16 bf16x8 __attribute__((ext_vector_type(8)));
typedef float f32x4 __attribute__((ext_vector_type(4)));

__device__ __forceinline__ unsigned pk2(float a, float b) {
    union { __hip_bfloat162 h; unsigned u; } c;
    c.h = __hip_bfloat162(__float2bfloat16(a), __float2bfloat16(b));
    return c.u;
}

// fp32 -> bf16 elementwise cast (RTN), n % 4 == 0.
__global__ __launch_bounds__(256) void cvt_f32_bf16(const float* __restrict__ src,
                                                    __hip_bfloat16* __restrict__ dst, int n) {
    int i = (blockIdx.x * 256 + threadIdx.x) * 4;
    if (i >= n) return;
    float4 f = *reinterpret_cast<const float4*>(src + i);
    dst[i + 0] = __float2bfloat16(f.x);
    dst[i + 1] = __float2bfloat16(f.y);
    dst[i + 2] = __float2bfloat16(f.z);
    dst[i + 3] = __float2bfloat16(f.w);
}

// 4 weight matrices (Dz*Dz each) -> contiguous bf16 dst in one launch.
__global__ __launch_bounds__(256) void cvt_w4(const float* __restrict__ w0, const float* __restrict__ w1,
                                              const float* __restrict__ w2, const float* __restrict__ w3,
                                              __hip_bfloat16* __restrict__ dst) {
    constexpr int WEL = Dz * Dz;  // 1<<20
    int i = (blockIdx.x * 256 + threadIdx.x) * 4;
    const int which = i >> 20;
    const float* src = (which == 0) ? w0 : (which == 1) ? w1 : (which == 2) ? w2 : w3;
    float4 f = *reinterpret_cast<const float4*>(src + (i & (WEL - 1)));
    dst[i + 0] = __float2bfloat16(f.x);
    dst[i + 1] = __float2bfloat16(f.y);
    dst[i + 2] = __float2bfloat16(f.z);
    dst[i + 3] = __float2bfloat16(f.w);
}

// async global -> LDS, 16 bytes per lane; LDS dest = uniform base + lane*16.
__device__ __forceinline__ void gl2lds16(const __hip_bfloat16* g, __hip_bfloat16* l) {
    __builtin_amdgcn_global_load_lds(
        (const __attribute__((address_space(1))) void*)g,
        (__attribute__((address_space(3))) void*)l, 16, 0, 0);
}

// Shared 128x128 GEMM block body (m97 structure, BK=32). C[M,N] = A @ W^T.
template <int N, int K, typename OT>
__device__ __forceinline__ void gemm128_body(const __hip_bfloat16* __restrict__ A,
                                             const __hip_bfloat16* __restrict__ W,
                                             OT* __restrict__ C, int bm, int bn,
                                             __hip_bfloat16* As, __hip_bfloat16* Bs) {
    const int tid  = threadIdx.x;
    const int wid  = tid >> 6;
    const int lane = tid & 63;
    const int quad = lane >> 4;
    const int l16  = lane & 15;
    const int wr = wid >> 1, wc = wid & 1;

    const int srow = wid * 32 + (lane >> 2);
    const int scol = (lane & 3) * 8;
    const __hip_bfloat16* gA = A + (size_t)(bm * 128 + srow) * K + scol;
    const __hip_bfloat16* gB = W + (size_t)(bn * 128 + srow) * K + scol;
    __hip_bfloat16* lA = &As[(wid * 32) * 32];
    __hip_bfloat16* lB = &Bs[(wid * 32) * 32];

    f32x4 acc[4][4] = {};

    for (int k0 = 0; k0 < K; k0 += 32) {
        __syncthreads();
        gl2lds16(gA + k0,                  lA);
        gl2lds16(gA + (size_t)16 * K + k0, lA + 16 * 32);
        gl2lds16(gB + k0,                  lB);
        gl2lds16(gB + (size_t)16 * K + k0, lB + 16 * 32);
        __syncthreads();

        bf16x8 af[4], bf[4];
#pragma unroll
        for (int mi = 0; mi < 4; ++mi)
            af[mi] = *reinterpret_cast<const bf16x8*>(&As[(wr * 64 + mi * 16 + l16) * 32 + quad * 8]);
#pragma unroll
        for (int ni = 0; ni < 4; ++ni)
            bf[ni] = *reinterpret_cast<const bf16x8*>(&Bs[(wc * 64 + ni * 16 + l16) * 32 + quad * 8]);
#pragma unroll
        for (int mi = 0; mi < 4; ++mi)
#pragma unroll
            for (int ni = 0; ni < 4; ++ni)
                acc[mi][ni] = __builtin_amdgcn_mfma_f32_16x16x32_bf16(af[mi], bf[ni], acc[mi][ni], 0, 0, 0);
    }

#pragma unroll
    for (int mi = 0; mi < 4; ++mi)
#pragma unroll
        for (int ni = 0; ni < 4; ++ni) {
            const size_t row0 = (size_t)(bm * 128 + wr * 64 + mi * 16 + quad * 4);
            const size_t col  = (size_t)(bn * 128 + wc * 64 + ni * 16 + l16);
#pragma unroll
            for (int r = 0; r < 4; ++r) {
                if constexpr (__is_same(OT, float))
                    C[(row0 + r) * N + col] = acc[mi][ni][r];
                else
                    C[(row0 + r) * N + col] = __float2bfloat16(acc[mi][ni][r]);
            }
        }
}

template <int M, int N, int K, typename OT>
__global__ __launch_bounds__(256) void gemm128(const __hip_bfloat16* __restrict__ A,
                                               const __hip_bfloat16* __restrict__ W,
                                               OT* __restrict__ C) {
    __shared__ __hip_bfloat16 As[128 * 32];
    __shared__ __hip_bfloat16 Bs[128 * 32];
    constexpr int NB = N / 128;
    gemm128_body<N, K, OT>(A, W, C, blockIdx.x / NB, blockIdx.x % NB, As, Bs);
}

// Fused QKV. which=0: Q = x·wq^T [8192,1024]; which=1: K = x·wk^T;
// which=2: V^T = wv·x^T, i.e. gemm(A=wv, W=x) -> C[outdim=h*64+dh][token=b*2048+s].
template <int M, int K>
__global__ __launch_bounds__(256) void gemm_qkv(const __hip_bfloat16* __restrict__ A,
                                                const __hip_bfloat16* __restrict__ W0,
                                                const __hip_bfloat16* __restrict__ W1,
                                                const __hip_bfloat16* __restrict__ W2,
                                                __hip_bfloat16* __restrict__ C0,
                                                __hip_bfloat16* __restrict__ C1,
                                                __hip_bfloat16* __restrict__ Vt) {
    __shared__ __hip_bfloat16 As[128 * 32];
    __shared__ __hip_bfloat16 Bs[128 * 32];
    const int which = blockIdx.x % 3;
    const int rem   = blockIdx.x / 3;
    if (which == 2) {
        // M'=1024 (outdims), N'=8192 (tokens): bm in 0..7, bn in 0..63
        gemm128_body<M, K, __hip_bfloat16>(W2, A, Vt, rem / (M / 128), rem % (M / 128), As, Bs);
    } else {
        const __hip_bfloat16* W = (which == 0) ? W0 : W1;
        __hip_bfloat16*       C = (which == 0) ? C0 : C1;
        gemm128_body<Dz, K, __hip_bfloat16>(A, W, C, rem / (Dz / 128), rem % (Dz / 128), As, Bs);
    }
}

#define SP 72  // PT leading stride in ushorts

// MFMA flash attention v6: BARRIER-FREE. V is pre-transposed in memory
// (Vt[outdim][token]) so PV's A-fragments are direct global b128 loads, like K.
// Only LDS use: tiny per-wave PT (P layout regroup) — no block-level sharing.
// Fixed-max exp2 softmax (shift-invariant, scores bounded), transposed-O accum,
// K/V register prefetch, causal pairing, XCD-local mapping.
__global__ __launch_bounds__(256) void attn_mfma6(const __hip_bfloat16* __restrict__ Q,
                                                  const __hip_bfloat16* __restrict__ Km,
                                                  const __hip_bfloat16* __restrict__ Vt,
                                                  __hip_bfloat16* __restrict__ O) {
    __shared__ unsigned short PT[4][16 * SP];    // per-wave P: [q][key-local]

    const int tid  = threadIdx.x;
    const int wid  = tid >> 6;
    const int lane = tid & 63;
    const int quad = lane >> 4;
    const int l16  = lane & 15;

    // XCD-local mapping: all 16 pair-blocks of a (b,h) share blockIdx%8 -> same XCD L2.
    const int xcd  = blockIdx.x & 7;
    const int j    = blockIdx.x >> 3;            // 0..127
    const int bh   = xcd * 8 + (j >> 4);         // 0..63
    const int pair = j & 15;
    const int h    = bh & 15;
    const int b    = bh >> 4;
    const size_t base = (size_t)b * Sz * Dz + (size_t)h * DHz;

    const __hip_bfloat16* kbase = Km + base + (size_t)l16 * Dz + quad * 8;
    // Vt row = h*64 + dh (dh = s*16 + l16), col = b*2048 + key
    const __hip_bfloat16* vtbase = Vt + ((size_t)(h * 64 + l16)) * (Bz * Sz) + (size_t)b * Sz + quad * 8;

    bf16x8 kf[4][2];   // K frags: 4 key-subtiles x 2 dh-halves
    bf16x8 vf[4][2];   // V^T frags: 4 dh-subtiles x 2 key-halves

    auto loadK = [&](int kn) {
        const __hip_bfloat16* kp = kbase + (size_t)kn * Dz;
#pragma unroll
        for (int s = 0; s < 4; ++s) {
            kf[s][0] = *reinterpret_cast<const bf16x8*>(kp + (size_t)(s * 16) * Dz);
            kf[s][1] = *reinterpret_cast<const bf16x8*>(kp + (size_t)(s * 16) * Dz + 32);
        }
    };
    auto loadV = [&](int kn) {
        const __hip_bfloat16* vp = vtbase + kn;
#pragma unroll
        for (int s = 0; s < 4; ++s) {
            vf[s][0] = *reinterpret_cast<const bf16x8*>(vp + (size_t)(s * 16) * (Bz * Sz));
            vf[s][1] = *reinterpret_cast<const bf16x8*>(vp + (size_t)(s * 16) * (Bz * Sz) + 32);
        }
    };

    constexpr float SC = 0.180336880f;  // (1/sqrt(64)) * log2(e): exp2-domain scores
    constexpr float FM = 16.0f;         // fixed max (log2 domain); true max ~4-7
    unsigned short* PTq = &PT[wid][l16 * SP];

#pragma unroll 1
    for (int p = 0; p < 2; ++p) {
        const int qblk  = (p == 0) ? pair : 31 - pair;
        const int q0    = qblk * 64 + wid * 16;
        const int niter = qblk + 1;

        const __hip_bfloat16* qp = Q + base + (size_t)(q0 + l16) * Dz + quad * 8;
        const bf16x8 qf0 = *reinterpret_cast<const bf16x8*>(qp);
        const bf16x8 qf1 = *reinterpret_cast<const bf16x8*>(qp + 32);

        float lp = 0.f;                          // per-lane partial sum of p
        f32x4 ot[4] = {};                        // O^T: col q=l16, rows dh=s*16+quad*4+r

        if (p == 0) { loadK(0); loadV(0); }      // p==1 tile 0 prefetched at end of p==0

#pragma unroll 1
        for (int it = 0; it < niter; ++it) {
            const int k0 = it * 64;
            const bool more = (it + 1 < niter);

            // S^T = K·Q^T : 8 MFMAs (C: row=key=quad*4+r, col=q=l16)
            f32x4 st[4] = {};
#pragma unroll
            for (int s = 0; s < 4; ++s) {
                st[s] = __builtin_amdgcn_mfma_f32_16x16x32_bf16(kf[s][0], qf0, st[s], 0, 0, 0);
                st[s] = __builtin_amdgcn_mfma_f32_16x16x32_bf16(kf[s][1], qf1, st[s], 0, 0, 0);
            }

            // kf consumed -> prefetch next K tile (in flight through softmax+PV)
            if (more)        loadK(k0 + 64);
            else if (p == 0) loadK(0);

            // fixed-max softmax: p = exp2(s*SC - FM); no cross-lane ops
            float psum = 0.f;
            unsigned pk[8];
            if (it == niter - 1) {               // block-uniform branch: diagonal tile
                const int qrow = q0 + l16;
#pragma unroll
                for (int s = 0; s < 4; ++s) {
                    float a[4];
#pragma unroll
                    for (int r = 0; r < 4; ++r) {
                        const int key = k0 + s * 16 + quad * 4 + r;
                        a[r] = (key <= qrow) ? exp2f(fmaf(st[s][r], SC, -FM)) : 0.f;
                    }
                    psum += (a[0] + a[1]) + (a[2] + a[3]);
                    pk[2 * s]     = pk2(a[0], a[1]);
                    pk[2 * s + 1] = pk2(a[2], a[3]);
                }
            } else {
#pragma unroll
                for (int s = 0; s < 4; ++s) {
                    float a[4];
#pragma unroll
                    for (int r = 0; r < 4; ++r)
                        a[r] = exp2f(fmaf(st[s][r], SC, -FM));
                    psum += (a[0] + a[1]) + (a[2] + a[3]);
                    pk[2 * s]     = pk2(a[0], a[1]);
                    pk[2 * s + 1] = pk2(a[2], a[3]);
                }
            }
            lp += psum;                          // quad-reduce deferred to epilogue

            // P -> PT[wid][q][key] (keys quad*4+r consecutive -> 8B stores; per-wave, no barrier)
#pragma unroll
            for (int s = 0; s < 4; ++s) {
                uint2 u; u.x = pk[2 * s]; u.y = pk[2 * s + 1];
                *reinterpret_cast<uint2*>(PTq + s * 16 + quad * 4) = u;
            }

            // PV (transposed): O^T[dh][q] += V^T·P; A=V^T frags (global), B=P from PT
            const bf16x8 pa0 = *reinterpret_cast<const bf16x8*>(PTq + quad * 8);
            const bf16x8 pa1 = *reinterpret_cast<const bf16x8*>(PTq + 32 + quad * 8);
#pragma unroll
            for (int s = 0; s < 4; ++s) {
                ot[s] = __builtin_amdgcn_mfma_f32_16x16x32_bf16(vf[s][0], pa0, ot[s], 0, 0, 0);
                ot[s] = __builtin_amdgcn_mfma_f32_16x16x32_bf16(vf[s][1], pa1, ot[s], 0, 0, 0);
            }

            // vf consumed -> prefetch next V tile (covered by next iter's QK+softmax)
            if (more)        loadV(k0 + 64);
            else if (p == 0) loadV(0);
        }

        // epilogue: reduce l across quads; lane (l16,quad) holds O[q=q0+l16][dh=s*16+quad*4+r]
        float lt = lp;
        lt += __shfl_xor(lt, 16, 64);
        lt += __shfl_xor(lt, 32, 64);
        const float inv = 1.f / lt;
        __hip_bfloat16* op = O + base + (size_t)(q0 + l16) * Dz + quad * 4;
#pragma unroll
        for (int s = 0; s < 4; ++s) {
            uint2 u;
            u.x = pk2(ot[s][0] * inv, ot[s][1] * inv);
            u.y = pk2(ot[s][2] * inv, ot[s][3] * inv);
            *reinterpret_cast<uint2*>(op + s * 16) = u;
        }
    }
}

extern "C" void kernel_launch(void* const* d_in, const int* in_sizes, int n_in,
                              void* d_out, int out_size, void* d_ws, size_t ws_size,
                              hipStream_t stream) {
    // Inputs fp32, output fp32. Internal compute bf16.
    const float* x  = (const float*)d_in[0];
    const float* wq = (const float*)d_in[1];
    const float* wk = (const float*)d_in[2];
    const float* wv = (const float*)d_in[3];
    const float* wo = (const float*)d_in[4];
    float* out = (float*)d_out;

    constexpr int TOK = Bz * Sz * Dz;   // 8,388,608
    constexpr int WEL = Dz * Dz;        // 1,048,576

    // ws: xb | wqb | wkb | wvb | wob | Qb | Kb (56 MB). Vt in d_out scratch; Ob aliases xb.
    __hip_bfloat16* xb  = (__hip_bfloat16*)d_ws;
    __hip_bfloat16* wqb = xb  + TOK;
    __hip_bfloat16* wkb = wqb + WEL;
    __hip_bfloat16* wvb = wkb + WEL;
    __hip_bfloat16* wob = wvb + WEL;
    __hip_bfloat16* Qb  = wob + WEL;
    __hip_bfloat16* Kb  = Qb + TOK;
    __hip_bfloat16* Vt  = (__hip_bfloat16*)d_out;  // V^T [1024 outdims][8192 tokens]; dead before final GEMM
    __hip_bfloat16* Ob  = xb;                      // x dead after QKV GEMM

    cvt_f32_bf16<<<TOK / 4 / 256, 256, 0, stream>>>(x, xb, TOK);
    cvt_w4<<<4 * WEL / 4 / 256, 256, 0, stream>>>(wq, wk, wv, wo, wqb);

    constexpr int M = Bz * Sz;                       // 8192
    constexpr int GB = (M / 128) * (Dz / 128);       // 512

    gemm_qkv<M, Dz><<<3 * GB, 256, 0, stream>>>(xb, wqb, wkb, wvb, Qb, Kb, Vt);

    const int ATTN_BLOCKS = Bz * Hz * 16;            // 1024 (paired q-blocks)
    attn_mfma6<<<ATTN_BLOCKS, 256, 0, stream>>>(Qb, Kb, Vt, Ob);

    gemm128<M, Dz, Dz, float><<<GB, 256, 0, stream>>>(Ob, wob, out);
}